// Round 14
// baseline (950.380 us; speedup 1.0000x reference)
//
#include <hip/hip_runtime.h>
#include <hip/hip_bf16.h>

// 2-layer LSTM (H=20) + FC(20->1), B=4096, T=512, D_in=1.
//
// Round-14: 8-WAVE LAYER x GATE SPLIT, one barrier/iter, zero AGPR parking.
// R13 analysis: 600 cyc/wave-iter = 390 VALU + 210 latency-idle; ~60 of the
// VALU are hidden accvgpr reads (60-float weight set parked because live
// ~130 > 64-arch comfort). Fix both:
//  - Block = 512 thr = 8 waves: wave (l,w) owns layer l, gate w. L0 waves
//    hold 11 weight pairs, L1 waves 20 pairs. h state NOT register-persistent:
//    re-read from LDS rows each iter (5x ds_read_b128, broadcast within each
//    20-lane group = conflict-free). Live/lane ~100 < cap 128
//    (__launch_bounds__(512,4)) -> all-arch, no accvgpr tax.
//  - Single barrier preserved by deepening the stagger: iter i runs L0 step i
//    and L1 step i-2. L1 reads h0(i-2) from a parity double-buffered SHARED
//    row (written by L0 gate-0 wave at B(i-2); BAR(i-1) lies between -> race-
//    free) and h1(i-3) from its own private row (intra-wave program order).
//  - NITER = T+2; L0 active i<T, L1 active i>=2 (wave-uniform guards).
// Gate formulas bitwise-identical to R13 (absmax 0.0 expected).
//
// Hazard ledger: act0/act1 parity-buffered (A(i) writes par i&1, B(i) reads
// after BAR; next same-parity write at A(i+2) is after BAR(i+1) which all
// B(i) readers passed). h0shar parity: write B(i-2), read A(i), rewrite
// B(i) - reader precedes BAR(i) which gates the rewrite. h0priv/h1priv:
// same-wave write->read only.

namespace {
constexpr int H_    = 20;
constexpr int T_    = 512;
constexpr int B_    = 4096;
constexpr int GPB   = 3;          // sequences per block
constexpr int NITER = T_ + 2;     // 514

typedef float __attribute__((ext_vector_type(2))) f32x2;

__device__ __forceinline__ float rcp_fast(float v) {
    return __builtin_amdgcn_rcpf(v);
}
__device__ __forceinline__ float sigm(float v) {
    return rcp_fast(1.0f + __expf(-v));
}
__device__ __forceinline__ float tanh_fast(float v) {
    return fmaf(-2.0f, rcp_fast(1.0f + __expf(2.0f * v)), 1.0f);
}
__device__ __forceinline__ void pk_mac(f32x2& acc, f32x2 a, f32x2 b) {
#if __has_builtin(__builtin_amdgcn_pk_fma_f32)
    acc = __builtin_amdgcn_pk_fma_f32(a, b, acc);
#else
    asm("v_pk_fma_f32 %0, %1, %2, %0" : "+v"(acc) : "v"(a), "v"(b));
#endif
}
} // namespace

__global__ __launch_bounds__(512, 4) void lstm2_fc_kernel(
    const float* __restrict__ x,
    const float* __restrict__ Wih0, const float* __restrict__ Whh0,
    const float* __restrict__ bih0, const float* __restrict__ bhh0,
    const float* __restrict__ Wih1, const float* __restrict__ Whh1,
    const float* __restrict__ bih1, const float* __restrict__ bhh1,
    const float* __restrict__ fcW,  const float* __restrict__ fcb,
    float* __restrict__ out)
{
    const int tid  = threadIdx.x;
    const int wv   = __builtin_amdgcn_readfirstlane(tid >> 6);  // 0..7
    const int isL1 = wv >> 2;                                   // 0 / 1
    const int w_s  = wv & 3;                                    // gate
    const int lane = tid & 63;
    const int g    = lane / H_;          // group 0..2 active, 3 = pad
    const int j    = lane - g * H_;      // hidden unit 0..19
    const int b    = blockIdx.x * GPB + g;
    const int gx   = (g < GPB) ? g : (GPB - 1);

    __shared__ float xs[GPB][T_];
    __shared__ float act0[2][4][64];                 // [parity][gate][lane]
    __shared__ float act1[2][4][64];
    __shared__ __align__(16) float h0priv[4][4][28]; // [L0 wave][group][unit]
    __shared__ __align__(16) float h0shar[2][4][28]; // [parity][group][unit]
    __shared__ __align__(16) float h1priv[4][4][28]; // [L1 wave][group][unit]

    // ---- stage x (coalesced) + zero h rows ----
    {
        const int base_b = blockIdx.x * GPB;
        for (int idx = tid; idx < GPB * T_; idx += 512) {
            const int gg = idx >> 9;            // /512
            const int tt = idx & (T_ - 1);      // %512
            int row = base_b + gg; if (row >= B_) row = B_ - 1;
            xs[gg][tt] = x[(size_t)row * T_ + tt];
        }
        float* hz = &h0priv[0][0][0];           // h0priv+h0shar+h1priv contiguous? not guaranteed; zero each
        (void)hz;
        for (int idx = tid; idx < 4 * 4 * 28; idx += 512) (&h0priv[0][0][0])[idx] = 0.0f;
        for (int idx = tid; idx < 2 * 4 * 28; idx += 512) (&h0shar[0][0][0])[idx] = 0.0f;
        for (int idx = tid; idx < 4 * 4 * 28; idx += 512) (&h1priv[0][0][0])[idx] = 0.0f;
    }

    // ---- per-role weights (all arch-resident; pinned) ----
    const int r = w_s * H_ + j;
    float w0x = 0.0f, bias = 0.0f;
    f32x2 wA[10], wB[10];
    if (!isL1) {
        w0x  = Wih0[r];                          // Wih0 is [80,1]
        bias = bih0[r] + bhh0[r];
        #pragma unroll
        for (int m = 0; m < 10; ++m) {
            f32x2 a = { Whh0[r * H_ + 2*m], Whh0[r * H_ + 2*m + 1] };
            wA[m] = a;
            f32x2 z = { 0.0f, 0.0f }; wB[m] = z;
        }
    } else {
        bias = bih1[r] + bhh1[r];
        #pragma unroll
        for (int m = 0; m < 10; ++m) {
            f32x2 a = { Wih1[r * H_ + 2*m], Wih1[r * H_ + 2*m + 1] };
            f32x2 c = { Whh1[r * H_ + 2*m], Whh1[r * H_ + 2*m + 1] };
            wA[m] = a; wB[m] = c;
        }
    }
    asm volatile("" : "+v"(w0x), "+v"(bias));
    #pragma unroll
    for (int m = 0; m < 10; ++m) asm volatile("" : "+v"(wA[m]), "+v"(wB[m]));

    float cst = 0.0f;                            // c0 (L0) / c1 (L1)

    const float4* h0privR = reinterpret_cast<const float4*>(&h0priv[w_s][gx][0]);
    const float4* h1privR = reinterpret_cast<const float4*>(&h1priv[w_s][gx][0]);

    __syncthreads();                             // xs + zeroed rows visible

    #pragma unroll 1
    for (int i = 0; i < NITER; ++i) {
        const int par = i & 1;

        // =================== phase A ===================
        if (!isL1) {
            if (i < T_) {                        // gate0(i), uses h0(i-1)
                f32x2 hp[10];
                #pragma unroll
                for (int c4 = 0; c4 < 5; ++c4) {
                    const float4 v = h0privR[c4];
                    f32x2 pa = { v.x, v.y }, pb = { v.z, v.w };
                    hp[2*c4] = pa; hp[2*c4+1] = pb;
                }
                f32x2 sA = {0.f,0.f}, sB = {0.f,0.f};
                #pragma unroll
                for (int m = 0; m < 10; m += 2) {
                    pk_mac(sA, wA[m    ], hp[m    ]);
                    pk_mac(sB, wA[m + 1], hp[m + 1]);
                }
                const float xv = xs[gx][i];
                const float gate = fmaf(w0x, xv, bias)
                                 + ((sA.x + sA.y) + (sB.x + sB.y));
                const float a = (w_s == 2) ? tanh_fast(gate) : sigm(gate);
                act0[par][w_s][lane] = a;
            }
        } else {
            if (i >= 2) {                        // gate1(i-2), uses h0(i-2), h1(i-3)
                f32x2 h0p[10], h1p[10];
                const float4* h0sh = reinterpret_cast<const float4*>(&h0shar[par][gx][0]);
                #pragma unroll
                for (int c4 = 0; c4 < 5; ++c4) {
                    const float4 v0 = h0sh[c4];
                    f32x2 a0 = { v0.x, v0.y }, b0 = { v0.z, v0.w };
                    h0p[2*c4] = a0; h0p[2*c4+1] = b0;
                    const float4 v1 = h1privR[c4];
                    f32x2 a1 = { v1.x, v1.y }, b1 = { v1.z, v1.w };
                    h1p[2*c4] = a1; h1p[2*c4+1] = b1;
                }
                f32x2 uA = {0.f,0.f}, uB = {0.f,0.f};
                f32x2 vA = {0.f,0.f}, vB = {0.f,0.f};
                #pragma unroll
                for (int m = 0; m < 10; m += 2) {
                    pk_mac(uA, wA[m    ], h0p[m    ]);
                    pk_mac(uB, wA[m + 1], h0p[m + 1]);
                    pk_mac(vA, wB[m    ], h1p[m    ]);
                    pk_mac(vB, wB[m + 1], h1p[m + 1]);
                }
                const float gate = (bias + ((uA.x + uA.y) + (uB.x + uB.y)))
                                 + ((vA.x + vA.y) + (vB.x + vB.y));
                const float a = (w_s == 2) ? tanh_fast(gate) : sigm(gate);
                act1[par][w_s][lane] = a;
            }
        }

        __syncthreads();                         // THE barrier

        // =================== phase B ===================
        if (!isL1) {
            if (i < T_) {                        // finalize h0(i)
                const float iv = act0[par][0][lane];
                const float fv = act0[par][1][lane];
                const float zv = act0[par][2][lane];
                const float ov = act0[par][3][lane];
                cst = fmaf(fv, cst, iv * zv);
                const float hn = ov * tanh_fast(cst);
                h0priv[w_s][g][j] = hn;          // own row (intra-wave RAW)
                if (w_s == 0) h0shar[par][g][j] = hn;   // for L1, 2 BARs later
            }
        } else {
            if (i >= 2) {                        // finalize h1(i-2)
                const float iv = act1[par][0][lane];
                const float fv = act1[par][1][lane];
                const float zv = act1[par][2][lane];
                const float ov = act1[par][3][lane];
                cst = fmaf(fv, cst, iv * zv);
                const float hn = ov * tanh_fast(cst);
                h1priv[w_s][g][j] = hn;          // own row (intra-wave RAW)
            }
        }
    }

    // ---- FC epilogue: h1priv[0] rows hold h1(T-1) (written B(513), wv==4) ----
    if (isL1 && w_s == 0 && g < GPB && j == 0 && b < B_) {
        float acc = fcb[0];
        #pragma unroll
        for (int k = 0; k < H_; ++k) acc = fmaf(fcW[k], h1priv[0][g][k], acc);
        out[b] = acc;
    }
}

extern "C" void kernel_launch(void* const* d_in, const int* in_sizes, int n_in,
                              void* d_out, int out_size, void* d_ws, size_t ws_size,
                              hipStream_t stream) {
    const float* x    = (const float*)d_in[0];
    const float* Wih0 = (const float*)d_in[1];
    const float* Whh0 = (const float*)d_in[2];
    const float* bih0 = (const float*)d_in[3];
    const float* bhh0 = (const float*)d_in[4];
    const float* Wih1 = (const float*)d_in[5];
    const float* Whh1 = (const float*)d_in[6];
    const float* bih1 = (const float*)d_in[7];
    const float* bhh1 = (const float*)d_in[8];
    const float* fcW  = (const float*)d_in[9];
    const float* fcb  = (const float*)d_in[10];
    float* out = (float*)d_out;

    const int grid = (B_ + GPB - 1) / GPB;   // 1366 blocks x 8 waves
    lstm2_fc_kernel<<<dim3(grid), dim3(512), 0, stream>>>(
        x, Wih0, Whh0, bih0, bhh0, Wih1, Whh1, bih1, bhh1, fcW, fcb, out);
}